// Round 5
// baseline (2615.971 us; speedup 1.0000x reference)
//
#include <hip/hip_runtime.h>

#define Hh 1024
#define NBATCH 128
#define TSTEPS 256
#define DOUT 1024
#define SLOT (NBATCH * Hh)

typedef _Float16 half8 __attribute__((ext_vector_type(8)));
typedef float floatx4 __attribute__((ext_vector_type(4)));

__device__ __forceinline__ float fast_sigmoid(float x) {
  float e = __expf(-x);
  return __builtin_amdgcn_rcpf(1.0f + e);
}
__device__ __forceinline__ float fast_tanh(float x) {
  x = fminf(15.0f, fmaxf(-15.0f, x));
  float e = __expf(-2.0f * x);
  return 1.0f - 2.0f * e * __builtin_amdgcn_rcpf(1.0f + e);
}

// Convert weights to f16, build W_sum = W_ih + W_hh, b_sum = b_ih + b_hh,
// stage hT as f16 into hs slot 0, zero per-wave flags (1024) + xcd ctrs (8).
__global__ void prep_kernel(const float* __restrict__ W_ih, const float* __restrict__ W_hh,
                            const float* __restrict__ W_fc, const float* __restrict__ b_ih,
                            const float* __restrict__ b_hh, const float* __restrict__ hT,
                            _Float16* __restrict__ w_ih_h, _Float16* __restrict__ w_sum_h,
                            _Float16* __restrict__ w_fc_h, float* __restrict__ b_sum,
                            _Float16* __restrict__ hs0, unsigned* __restrict__ flags) {
  int i0 = blockIdx.x * blockDim.x + threadIdx.x;
  int stride = gridDim.x * blockDim.x;
  for (int i = i0; i < 4096 * 1024; i += stride) {
    float a = W_ih[i];
    w_ih_h[i] = (_Float16)a;
    w_sum_h[i] = (_Float16)(a + W_hh[i]);
  }
  for (int i = i0; i < 1024 * 1024; i += stride) w_fc_h[i] = (_Float16)W_fc[i];
  for (int i = i0; i < 4096; i += stride) b_sum[i] = b_ih[i] + b_hh[i];
  for (int i = i0; i < NBATCH * Hh; i += stride) hs0[i] = (_Float16)hT[i];
  for (int i = i0; i < 1032; i += stride) flags[i] = 0;
}

// Persistent LSTM kernel: 256 WGs (one per CU), 4 waves each, XCD-local
// groups via HW_REG_XCC_ID self-assignment (proven: FETCH 275->98MB).
//
// Synchronization (v5) = v2's PROVEN drain-then-flag ordering, made per-wave:
//  - h stored as packed DWORDS (lane-pair shfl_xor swap: each thread's two
//    u16 values for rows r0/r1 at col c become one aligned dword at (row,
//    2-col)) via relaxed AGENT write-through stores. Halves the number of
//    fabric messages vs 2B stores (v4 lesson: sub-dword WT stores are slow).
//  - each wave drains ITS OWN stores (s_waitcnt vmcnt(0)) then stores its
//    per-wave flag (AGENT atomic). Data->flag order preserved per-wave;
//    the WG-wide second __syncthreads of v2 is deleted.
//  - consumer wave polls the 32 per-wave producer flags covering its
//    K-range (one 128B line, relaxed AGENT atomic loads - v2-proven fast
//    path), then PLAIN dwordx4 A-loads (XCD-L2 broadcast-amplified: 32 WGs
//    share each 32KB slot; flags guarantee the coherence point holds
//    complete lines, so the first L2 fill is clean).
//  - single raw s_barrier per step (lgkmcnt only) + double-buffered LDS
//    reduce buffer (waves stay within one barrier generation; writers
//    touch pb, post-barrier stragglers read pb^1).
__global__ __launch_bounds__(256, 1) void lstm_kernel(
    const _Float16* __restrict__ w_ih_h, const _Float16* __restrict__ w_sum_h,
    const float* __restrict__ b_sum, _Float16* __restrict__ hs,
    unsigned* __restrict__ flags) {
  unsigned* xcd_ctr = flags + 1024;
  const int tid = threadIdx.x;
  const int wave = tid >> 6;
  const int lane = tid & 63;
  const int l15 = lane & 15;
  const int quad = lane >> 4;

  __shared__ unsigned role_sh;
  {
    unsigned xcd;
    asm volatile("s_getreg_b32 %0, hwreg(HW_REG_XCC_ID)" : "=s"(xcd));
    if (tid == 0) role_sh = (xcd << 8) | atomicAdd(&xcd_ctr[xcd], 1u);
  }
  __syncthreads();
  const int g = role_sh >> 8;    // physical XCD == n-group
  const int jb = role_sh & 255;  // 0..31 within the XCD
  const int n0 = g * 16;
  const int j0 = jb * 32;
  const int kbase = wave * 256;
  const int oc = wave >> 1;  // ct half this wave reduces/owns
  const int rp = wave & 1;   // accumulator reg-pair this wave reduces/owns

  // per-wave flags: flags[g*128 + jb*4 + wv]
  unsigned* myflag = flags + g * 128 + jb * 4 + wave;
  // consumer wave w polls jb' in [8w,8w+8) x 4 waves = 32 consecutive slots
  unsigned* pollp = flags + g * 128 + wave * 32 + (lane & 31);

  __shared__ float2 part[2][4][2][4][2][64];  // [pb][src][ct][gate][rpair][lane] = 64KB

  float bias[4];
#pragma unroll
  for (int gt = 0; gt < 4; ++gt) bias[gt] = b_sum[gt * 1024 + j0 + oc * 16 + l15];

  half8 B[4][2][8];             // 256 regs of resident weights per lane
  float cst[2] = {0.0f, 0.0f};  // persistent cell state (this thread's 2 slots)

  const int odd = l15 & 1;
  // dword store target: even lane -> (row r0, cols c..c+1); odd -> (r1, c-1..c)
  const int myrow_base = n0 + quad * 4 + rp * 2;  // r0; +1 for odd lanes

  auto load_B = [&](const _Float16* w) {
#pragma unroll
    for (int gt = 0; gt < 4; ++gt)
#pragma unroll
      for (int ct = 0; ct < 2; ++ct) {
        const _Float16* p =
            w + (size_t)(gt * 1024 + j0 + ct * 16 + l15) * Hh + kbase + quad * 8;
#pragma unroll
        for (int ks = 0; ks < 8; ++ks) B[gt][ct][ks] = *(const half8*)(p + ks * 32);
      }
  };

  auto do_step = [&](const _Float16* hsrc, _Float16* hdst, int s, int pb, bool setflag) {
    // 1) flag poll: one 128B line of per-wave producer flags (v2-proven path)
    if (s > 0) {
      while (1) {
        unsigned v = __hip_atomic_load(pollp, __ATOMIC_RELAXED, __HIP_MEMORY_SCOPE_AGENT);
        if (__all((int)(v >= (unsigned)s))) break;
      }
    }
    asm volatile("" ::: "memory");  // keep A-loads below the poll exit
    // 2) plain A-loads (XCD-L2 amplified; coherence point complete per flags)
    const _Float16* ap = hsrc + (size_t)(n0 + l15) * Hh + kbase + quad * 8;
    half8 Af[8];
#pragma unroll
    for (int ks = 0; ks < 8; ++ks) Af[ks] = *(const half8*)(ap + ks * 32);

    floatx4 acc[2][4] = {};
#pragma unroll
    for (int ks = 0; ks < 8; ++ks)
#pragma unroll
      for (int ct = 0; ct < 2; ++ct)
#pragma unroll
        for (int gt = 0; gt < 4; ++gt)
          acc[ct][gt] =
              __builtin_amdgcn_mfma_f32_16x16x32_f16(Af[ks], B[gt][ct][ks], acc[ct][gt], 0, 0, 0);

#pragma unroll
    for (int ct = 0; ct < 2; ++ct)
#pragma unroll
      for (int gt = 0; gt < 4; ++gt) {
        float2 lo, hi;
        lo.x = acc[ct][gt][0]; lo.y = acc[ct][gt][1];
        hi.x = acc[ct][gt][2]; hi.y = acc[ct][gt][3];
        part[pb][wave][ct][gt][0][lane] = lo;
        part[pb][wave][ct][gt][1][lane] = hi;
      }
    // single barrier per step: LDS visibility only, NO vmcnt drain.
    asm volatile("s_waitcnt lgkmcnt(0)" ::: "memory");
    __builtin_amdgcn_sched_barrier(0);
    __builtin_amdgcn_s_barrier();
    __builtin_amdgcn_sched_barrier(0);

    float gv[4][2];
#pragma unroll
    for (int gt = 0; gt < 4; ++gt) {
      float2 sv = part[pb][0][oc][gt][rp][lane];
#pragma unroll
      for (int src = 1; src < 4; ++src) {
        float2 p = part[pb][src][oc][gt][rp][lane];
        sv.x += p.x; sv.y += p.y;
      }
      gv[gt][0] = sv.x + bias[gt];
      gv[gt][1] = sv.y + bias[gt];
    }
    unsigned hu[2];
#pragma unroll
    for (int rr = 0; rr < 2; ++rr) {
      float ig = fast_sigmoid(gv[0][rr]);
      float fg = fast_sigmoid(gv[1][rr]);
      float gg = fast_tanh(gv[2][rr]);
      float og = fast_sigmoid(gv[3][rr]);
      float c = fg * cst[rr] + ig * gg;
      cst[rr] = c;
      float h = og * fast_tanh(c);
      _Float16 hv = (_Float16)h;
      unsigned short ub;
      __builtin_memcpy(&ub, &hv, 2);
      hu[rr] = ub;
    }
    // lane-pair swap: even lane ends with (row r0, cols c,c+1), odd with
    // (row r1, cols c-1,c) -> one aligned dword store per thread.
    unsigned send = odd ? hu[0] : hu[1];
    unsigned recv = (unsigned)__shfl_xor((int)send, 1, 64);
    unsigned lo16 = odd ? recv : hu[0];
    unsigned hi16 = odd ? hu[1] : recv;
    unsigned dw = (lo16 & 0xffffu) | (hi16 << 16);
    int row = myrow_base + odd;
    int col = j0 + oc * 16 + l15 - odd;
    __hip_atomic_store((unsigned*)(hdst + (size_t)row * Hh + col), dw,
                       __ATOMIC_RELAXED, __HIP_MEMORY_SCOPE_AGENT);
    if (setflag) {
      // per-wave drain-then-flag: THIS wave's h stores are at the coherence
      // point before its flag is issued (v2-proven ordering, minus the
      // WG-wide barrier).
      asm volatile("s_waitcnt vmcnt(0)" ::: "memory");
      if (lane == 0) {
        __hip_atomic_store(myflag, (unsigned)(s + 1), __ATOMIC_RELAXED,
                           __HIP_MEMORY_SCOPE_AGENT);
      }
    }
  };

  // Step 0: x = hT (slot 0), hx = 0 => gates = hT @ W_ih^T + b_sum
  load_B(w_ih_h);
  do_step(hs, hs + SLOT, 0, 0, true);
  // Steps 1..255: x = hx = h => gates = h @ (W_ih+W_hh)^T + b_sum
  load_B(w_sum_h);
  for (int s = 1; s < TSTEPS; ++s)
    do_step(hs + (size_t)s * SLOT, hs + (size_t)(s + 1) * SLOT, s, s & 1, s < TSTEPS - 1);
}

// recons[n, s, :] = h_s @ W_fc^T + b_fc.  A = hs slots 1..256 viewed as
// [32768 x 1024] f16 (row r = s*128 + n). 64x64 tiles, 4 waves of 16 rows.
__global__ __launch_bounds__(256) void fc_kernel(const _Float16* __restrict__ A,
                                                 const _Float16* __restrict__ Bw,
                                                 const float* __restrict__ b_fc,
                                                 float* __restrict__ out) {
  const int nb = blockIdx.x;  // 0..15  (d blocks of 64)
  const int mb = blockIdx.y;  // 0..511 (row blocks of 64)
  const int tid = threadIdx.x;
  const int wave = tid >> 6;
  const int lane = tid & 63;
  const int l15 = lane & 15;
  const int quad = lane >> 4;
  const int m0 = mb * 64 + wave * 16;
  const int d0 = nb * 64;

  floatx4 acc[4] = {};
  const _Float16* ap = A + (size_t)(m0 + l15) * Hh + quad * 8;
  const _Float16* bp = Bw + (size_t)(d0 + l15) * Hh + quad * 8;
#pragma unroll 4
  for (int k = 0; k < Hh; k += 32) {
    half8 a = *(const half8*)(ap + k);
#pragma unroll
    for (int ct = 0; ct < 4; ++ct) {
      half8 b = *(const half8*)(bp + (size_t)ct * 16 * Hh + k);
      acc[ct] = __builtin_amdgcn_mfma_f32_16x16x32_f16(a, b, acc[ct], 0, 0, 0);
    }
  }
#pragma unroll
  for (int ct = 0; ct < 4; ++ct) {
    int d = d0 + ct * 16 + l15;
    float bv = b_fc[d];
#pragma unroll
    for (int r = 0; r < 4; ++r) {
      int row = m0 + quad * 4 + r;
      int s = row >> 7;
      int n = row & 127;
      out[((size_t)n * TSTEPS + s) * DOUT + d] = acc[ct][r] + bv;
    }
  }
}

extern "C" void kernel_launch(void* const* d_in, const int* in_sizes, int n_in,
                              void* d_out, int out_size, void* d_ws, size_t ws_size,
                              hipStream_t stream) {
  const float* hT   = (const float*)d_in[0];
  const float* W_ih = (const float*)d_in[1];
  const float* W_hh = (const float*)d_in[2];
  const float* b_ih = (const float*)d_in[3];
  const float* b_hh = (const float*)d_in[4];
  const float* W_fc = (const float*)d_in[5];
  const float* b_fc = (const float*)d_in[6];
  float* out = (float*)d_out;

  char* ws = (char*)d_ws;
  unsigned* flags   = (unsigned*)ws;                    // per-wave flags[1024] + xcd_ctr[8]
  float* b_sum      = (float*)(ws + 8192);              // 16KB
  _Float16* w_ih_h  = (_Float16*)(ws + 65536);          // 8MB
  _Float16* w_sum_h = w_ih_h + (size_t)4096 * 1024;     // 8MB
  _Float16* w_fc_h  = w_sum_h + (size_t)4096 * 1024;    // 2MB
  _Float16* hs      = w_fc_h + (size_t)1024 * 1024;     // 257 * 256KB = 67.3MB

  prep_kernel<<<4096, 256, 0, stream>>>(W_ih, W_hh, W_fc, b_ih, b_hh, hT,
                                        w_ih_h, w_sum_h, w_fc_h, b_sum, hs, flags);
  lstm_kernel<<<256, 256, 0, stream>>>(w_ih_h, w_sum_h, b_sum, hs, flags);
  fc_kernel<<<dim3(16, 512), 256, 0, stream>>>(hs + SLOT, w_fc_h, b_fc, out);
}

// Round 6
// 1334.910 us; speedup vs baseline: 1.9597x; 1.9597x over previous
//
#include <hip/hip_runtime.h>

#define Hh 1024
#define NBATCH 128
#define TSTEPS 256
#define DOUT 1024
#define SLOT (NBATCH * Hh)

typedef _Float16 half8 __attribute__((ext_vector_type(8)));
typedef float floatx4 __attribute__((ext_vector_type(4)));

__device__ __forceinline__ float fast_sigmoid(float x) {
  float e = __expf(-x);
  return __builtin_amdgcn_rcpf(1.0f + e);
}
__device__ __forceinline__ float fast_tanh(float x) {
  x = fminf(15.0f, fmaxf(-15.0f, x));
  float e = __expf(-2.0f * x);
  return 1.0f - 2.0f * e * __builtin_amdgcn_rcpf(1.0f + e);
}

// Convert weights to f16, build W_sum = W_ih + W_hh, b_sum = b_ih + b_hh,
// stage hT as f16 into hs slot 0, zero flags (256) + per-XCD counters (8).
__global__ void prep_kernel(const float* __restrict__ W_ih, const float* __restrict__ W_hh,
                            const float* __restrict__ W_fc, const float* __restrict__ b_ih,
                            const float* __restrict__ b_hh, const float* __restrict__ hT,
                            _Float16* __restrict__ w_ih_h, _Float16* __restrict__ w_sum_h,
                            _Float16* __restrict__ w_fc_h, float* __restrict__ b_sum,
                            _Float16* __restrict__ hs0, unsigned* __restrict__ flags) {
  int i0 = blockIdx.x * blockDim.x + threadIdx.x;
  int stride = gridDim.x * blockDim.x;
  for (int i = i0; i < 4096 * 1024; i += stride) {
    float a = W_ih[i];
    w_ih_h[i] = (_Float16)a;
    w_sum_h[i] = (_Float16)(a + W_hh[i]);
  }
  for (int i = i0; i < 1024 * 1024; i += stride) w_fc_h[i] = (_Float16)W_fc[i];
  for (int i = i0; i < 4096; i += stride) b_sum[i] = b_ih[i] + b_hh[i];
  for (int i = i0; i < NBATCH * Hh; i += stride) hs0[i] = (_Float16)hT[i];
  for (int i = i0; i < 512; i += stride) flags[i] = 0;  // flags[256] + xcd_ctr[8]
}

// Persistent LSTM kernel: 256 WGs (one per CU), 4 waves each, XCD-local
// groups via HW_REG_XCC_ID self-assignment. EXACT round-2 structure
// (960 us proven): two __syncthreads per step, per-WG flag after the
// vmcnt-draining barrier, per-wave fine-grained poll of 8 producer WG flags.
// v3/v4/v5 each deviated from this sync discipline and all regressed.
__global__ __launch_bounds__(256, 1) void lstm_kernel(
    const _Float16* __restrict__ w_ih_h, const _Float16* __restrict__ w_sum_h,
    const float* __restrict__ b_sum, _Float16* __restrict__ hs,
    unsigned* __restrict__ flags) {
  unsigned* xcd_ctr = flags + 256;
  const int tid = threadIdx.x;
  const int wave = tid >> 6;
  const int lane = tid & 63;
  const int l15 = lane & 15;
  const int quad = lane >> 4;

  __shared__ unsigned role_sh;
  {
    unsigned xcd;
    asm volatile("s_getreg_b32 %0, hwreg(HW_REG_XCC_ID)" : "=s"(xcd));
    if (tid == 0) role_sh = (xcd << 8) | atomicAdd(&xcd_ctr[xcd], 1u);
  }
  __syncthreads();
  const int g = role_sh >> 8;    // physical XCD == n-group
  const int jb = role_sh & 255;  // 0..31 within the XCD
  const int n0 = g * 16;
  const int j0 = jb * 32;
  const int kbase = wave * 256;
  const int oc = wave >> 1;  // ct half this wave reduces/owns
  const int rp = wave & 1;   // accumulator reg-pair this wave reduces/owns

  unsigned* gflags = flags + g * 32;
  unsigned* pollp = gflags + wave * 8 + (lane & 7);

  __shared__ float2 part[4][2][4][2][64];  // [src][ct][gate][rpair][lane] = 32KB

  float bias[4];
#pragma unroll
  for (int gt = 0; gt < 4; ++gt) bias[gt] = b_sum[gt * 1024 + j0 + oc * 16 + l15];

  half8 B[4][2][8];             // 256 regs of resident weights per lane
  float cst[2] = {0.0f, 0.0f};  // persistent cell state (this thread's 2 slots)

  auto load_B = [&](const _Float16* w) {
#pragma unroll
    for (int gt = 0; gt < 4; ++gt)
#pragma unroll
      for (int ct = 0; ct < 2; ++ct) {
        const _Float16* p =
            w + (size_t)(gt * 1024 + j0 + ct * 16 + l15) * Hh + kbase + quad * 8;
#pragma unroll
        for (int ks = 0; ks < 8; ++ks) B[gt][ct][ks] = *(const half8*)(p + ks * 32);
      }
  };

  auto poll = [&](int tgt) {
    while (1) {
      unsigned v = __hip_atomic_load(pollp, __ATOMIC_RELAXED, __HIP_MEMORY_SCOPE_AGENT);
      if (__all((int)(v >= (unsigned)tgt))) break;
    }
  };

  auto do_step = [&](const _Float16* hsrc, _Float16* hdst, int sready, bool setflag) {
    poll(sready);  // wait only for this wave's 8 producers
    floatx4 acc[2][4] = {};
    const _Float16* ap = hsrc + (size_t)(n0 + l15) * Hh + kbase + quad * 8;
#pragma unroll
    for (int ks = 0; ks < 8; ++ks) {
      half8 a = *(const half8*)(ap + ks * 32);
#pragma unroll
      for (int ct = 0; ct < 2; ++ct)
#pragma unroll
        for (int gt = 0; gt < 4; ++gt)
          acc[ct][gt] =
              __builtin_amdgcn_mfma_f32_16x16x32_f16(a, B[gt][ct][ks], acc[ct][gt], 0, 0, 0);
    }
#pragma unroll
    for (int ct = 0; ct < 2; ++ct)
#pragma unroll
      for (int gt = 0; gt < 4; ++gt) {
        float2 lo, hi;
        lo.x = acc[ct][gt][0]; lo.y = acc[ct][gt][1];
        hi.x = acc[ct][gt][2]; hi.y = acc[ct][gt][3];
        part[wave][ct][gt][0][lane] = lo;
        part[wave][ct][gt][1][lane] = hi;
      }
    __syncthreads();

    float gv[4][2];
#pragma unroll
    for (int gt = 0; gt < 4; ++gt) {
      float2 s = part[0][oc][gt][rp][lane];
#pragma unroll
      for (int src = 1; src < 4; ++src) {
        float2 p = part[src][oc][gt][rp][lane];
        s.x += p.x; s.y += p.y;
      }
      gv[gt][0] = s.x + bias[gt];
      gv[gt][1] = s.y + bias[gt];
    }
#pragma unroll
    for (int rr = 0; rr < 2; ++rr) {
      float ig = fast_sigmoid(gv[0][rr]);
      float fg = fast_sigmoid(gv[1][rr]);
      float gg = fast_tanh(gv[2][rr]);
      float og = fast_sigmoid(gv[3][rr]);
      float c = fg * cst[rr] + ig * gg;
      cst[rr] = c;
      float h = og * fast_tanh(c);
      int row = n0 + quad * 4 + rp * 2 + rr;
      _Float16 hv = (_Float16)h;
      unsigned short ub;
      __builtin_memcpy(&ub, &hv, 2);
      // sc1 write-through store: visible at the coherent point once vmcnt
      // retires; no dirty L2 line left behind.
      __hip_atomic_store((unsigned short*)(hdst + (size_t)row * Hh + j0 + oc * 16 + l15),
                         ub, __ATOMIC_RELAXED, __HIP_MEMORY_SCOPE_AGENT);
    }
    // Drains vmcnt(0) (h stores reach coherent point) + protects LDS reuse.
    __syncthreads();
    if (setflag && tid == 0) {
      __hip_atomic_store(&gflags[jb], (unsigned)(sready + 1), __ATOMIC_RELAXED,
                         __HIP_MEMORY_SCOPE_AGENT);
    }
  };

  // Step 0: x = hT, hx = 0  =>  gates = hT @ W_ih^T + b_sum
  load_B(w_ih_h);
  do_step(hs, hs + SLOT, 0, true);
  // Steps 1..255: x = hx = h  =>  gates = h @ (W_ih+W_hh)^T + b_sum
  load_B(w_sum_h);
  for (int s = 1; s < TSTEPS; ++s)
    do_step(hs + (size_t)s * SLOT, hs + (size_t)(s + 1) * SLOT, s, s < TSTEPS - 1);
}

// recons[n, s, :] = h_s @ W_fc^T + b_fc.  A = hs slots 1..256 viewed as
// [32768 x 1024] f16 (row r = s*128 + n).
// v6: 128x128 tile per WG, 4 waves in 2x2, each wave computes 64x64
// (4x4 MFMA fragments) -> loads/MFMA = 0.5 (was 1.25). XCD-aware block
// mapping: bid%8 = XCD (round-robin dispatch); consecutive same-XCD WGs
// iterate all 8 d-blocks of ONE A-panel (nb fastest) so the 256KB A-panel
// is fetched once per XCD and B (2MB) stays L2-resident.
__global__ __launch_bounds__(256) void fc_kernel(const _Float16* __restrict__ A,
                                                 const _Float16* __restrict__ Bw,
                                                 const float* __restrict__ b_fc,
                                                 float* __restrict__ out) {
  const int bid = blockIdx.x;      // 0..2047
  const int c = bid & 7;           // XCD under round-robin dispatch
  const int q = bid >> 3;          // per-XCD sequence 0..255
  const int nb = q & 7;            // d-block 0..7 (fastest within XCD)
  const int mb = (q >> 3) * 8 + c; // row-block 0..255
  const int tid = threadIdx.x;
  const int wave = tid >> 6;
  const int lane = tid & 63;
  const int l15 = lane & 15;
  const int quad = lane >> 4;
  const int m0 = mb * 128 + (wave >> 1) * 64;
  const int d0 = nb * 128 + (wave & 1) * 64;

  floatx4 acc[4][4] = {};
  const _Float16* ap = A + (size_t)(m0 + l15) * Hh + quad * 8;
  const _Float16* bp = Bw + (size_t)(d0 + l15) * Hh + quad * 8;
#pragma unroll 2
  for (int k = 0; k < Hh; k += 32) {
    half8 a[4], b[4];
#pragma unroll
    for (int i = 0; i < 4; ++i) {
      a[i] = *(const half8*)(ap + (size_t)i * 16 * Hh + k);
      b[i] = *(const half8*)(bp + (size_t)i * 16 * Hh + k);
    }
#pragma unroll
    for (int mt = 0; mt < 4; ++mt)
#pragma unroll
      for (int ct = 0; ct < 4; ++ct)
        acc[mt][ct] = __builtin_amdgcn_mfma_f32_16x16x32_f16(a[mt], b[ct], acc[mt][ct], 0, 0, 0);
  }
#pragma unroll
  for (int ct = 0; ct < 4; ++ct) {
    int d = d0 + ct * 16 + l15;
    float bv = b_fc[d];
#pragma unroll
    for (int mt = 0; mt < 4; ++mt)
#pragma unroll
      for (int r = 0; r < 4; ++r) {
        int row = m0 + mt * 16 + quad * 4 + r;
        int s = row >> 7;
        int n = row & 127;
        out[((size_t)n * TSTEPS + s) * DOUT + d] = acc[mt][ct][r] + bv;
      }
  }
}

extern "C" void kernel_launch(void* const* d_in, const int* in_sizes, int n_in,
                              void* d_out, int out_size, void* d_ws, size_t ws_size,
                              hipStream_t stream) {
  const float* hT   = (const float*)d_in[0];
  const float* W_ih = (const float*)d_in[1];
  const float* W_hh = (const float*)d_in[2];
  const float* b_ih = (const float*)d_in[3];
  const float* b_hh = (const float*)d_in[4];
  const float* W_fc = (const float*)d_in[5];
  const float* b_fc = (const float*)d_in[6];
  float* out = (float*)d_out;

  char* ws = (char*)d_ws;
  unsigned* flags   = (unsigned*)ws;                    // flags[256] + xcd_ctr[8]
  float* b_sum      = (float*)(ws + 4096);              // 16KB
  _Float16* w_ih_h  = (_Float16*)(ws + 65536);          // 8MB
  _Float16* w_sum_h = w_ih_h + (size_t)4096 * 1024;     // 8MB
  _Float16* w_fc_h  = w_sum_h + (size_t)4096 * 1024;    // 2MB
  _Float16* hs      = w_fc_h + (size_t)1024 * 1024;     // 257 * 256KB = 67.3MB

  prep_kernel<<<4096, 256, 0, stream>>>(W_ih, W_hh, W_fc, b_ih, b_hh, hT,
                                        w_ih_h, w_sum_h, w_fc_h, b_sum, hs, flags);
  lstm_kernel<<<256, 256, 0, stream>>>(w_ih_h, w_sum_h, b_sum, hs, flags);
  fc_kernel<<<2048, 256, 0, stream>>>(hs + SLOT, w_fc_h, b_fc, out);
}